// Round 12
// baseline (115.277 us; speedup 1.0000x reference)
//
#include <hip/hip_runtime.h>
#include <hip/hip_fp16.h>
#include <stdint.h>

#define FM_BATCH 16384
#define ND 13
#define NF 26
#define FS 100000
#define FL 2600013            // 26*100000 + 13
#define FL_PAD 2600192        // 10157 * 256

// ws layout: flags [FL_PAD] bytes (2.6 MB), then Vt [FL_PAD][16] u32 (166 MB)
#define N_MARK  (FM_BATCH * NF)         // 425984

// component cc of a float4, cc a compile-time constant after unrolling
#define COMP(v, cc) ((cc) == 0 ? (v).x : (cc) == 1 ? (v).y : (cc) == 2 ? (v).z : (v).w)

// ---- Kernel 0: mark referenced features (races write the same value 1) ----
__global__ __launch_bounds__(256) void fm_mark(const int* __restrict__ sparse,
                                               unsigned char* __restrict__ flags)
{
    const int t = blockIdx.x * 256 + threadIdx.x;   // t = b*26 + f, flat over sparse
    const int f = t % NF;
    flags[ND + f * FS + sparse[t]] = 1;
    if (t < ND) flags[t] = 1;                       // dense features always present
}

// ---- Kernel 1: transpose + fp16-quantize referenced columns of V ----
// Each thread owns 4 consecutive columns and reads float4 (dwordx4): a wave
// request covers 1 KB contiguous of one k-row (vs 256 B with dword) -> 4x
// fewer requests for the same 333 MB, targeting the float4-copy BW regime.
// Rows processed in 8-row chunks to bound VGPRs; transpose in registers
// (all vector-component indices compile-time -> no scratch).
// Reads unconditional (R10: masking reads cost 8.6 us); cvt+store flag-gated.
__global__ __launch_bounds__(256) void fm_prep(const float* __restrict__ V,
                                               const unsigned char* __restrict__ flags,
                                               unsigned* __restrict__ Vt)
{
    const int j0 = (blockIdx.x * 256 + threadIdx.x) * 4;
    if (j0 >= FL) return;

    // 4 flag bytes in one aligned dword (padding bytes are zero)
    const unsigned fw = *reinterpret_cast<const unsigned*>(flags + j0);

    if (j0 + 3 < FL) {
        float4 va[8];
#pragma unroll
        for (int c = 0; c < 4; ++c) {               // row chunk: rows 8c..8c+7
#pragma unroll
            for (int r = 0; r < 8; ++r)
                va[r] = *reinterpret_cast<const float4*>(&V[(size_t)(c * 8 + r) * FL + j0]);
#pragma unroll
            for (int r = 0; r < 8; ++r)             // keep loads un-sunk
                asm volatile("" :: "v"(va[r].x), "v"(va[r].y), "v"(va[r].z), "v"(va[r].w));
#pragma unroll
            for (int cc = 0; cc < 4; ++cc) {
                if ((fw >> (8 * cc)) & 0xffu) {
                    unsigned pk[4];
#pragma unroll
                    for (int r2 = 0; r2 < 4; ++r2) {
                        const float a = COMP(va[2 * r2], cc);
                        const float b = COMP(va[2 * r2 + 1], cc);
                        pk[r2] = (unsigned)__half_as_ushort(__float2half_rn(a)) |
                                 ((unsigned)__half_as_ushort(__float2half_rn(b)) << 16);
                    }
                    *reinterpret_cast<uint4*>(Vt + (size_t)(j0 + cc) * 16 + c * 4) =
                        make_uint4(pk[0], pk[1], pk[2], pk[3]);
                }
            }
        }
    } else {
        // tail (at most one thread-group straddles FL): scalar per column
        for (int cc = 0; cc < 4; ++cc) {
            const int j = j0 + cc;
            if (j >= FL) break;
            if (!((fw >> (8 * cc)) & 0xffu)) continue;
            unsigned pk[16];
            for (int r = 0; r < 16; ++r) {
                const float a = V[(size_t)(2 * r) * FL + j];
                const float b = V[(size_t)(2 * r + 1) * FL + j];
                pk[r] = (unsigned)__half_as_ushort(__float2half_rn(a)) |
                        ((unsigned)__half_as_ushort(__float2half_rn(b)) << 16);
            }
            for (int c = 0; c < 4; ++c)
                *reinterpret_cast<uint4*>(Vt + (size_t)j * 16 + 4 * c) =
                    make_uint4(pk[4 * c], pk[4 * c + 1], pk[4 * c + 2], pk[4 * c + 3]);
        }
    }
}

// ---- Kernel 2: the whole FM. 32 lanes/sample = 16 k-lanes x 2 field-halves.
// 2048 blocks -> 32 waves/CU (max occupancy).
__global__ __launch_bounds__(256) void fm_gather(
    const float* __restrict__ dense,   // [BATCH][13]
    const int*   __restrict__ sparse,  // [BATCH][26]
    const float* __restrict__ w0,      // [1]
    const float* __restrict__ w,       // [FL]
    const unsigned* __restrict__ Vt,   // [FL_PAD][16] u32 (32 fp16)
    float* __restrict__ out)           // [BATCH]
{
    const int tid = blockIdx.x * 256 + threadIdx.x;
    const int b = tid >> 5;            // sample
    const int lane32 = tid & 31;
    const int q = lane32 & 15;         // k-pair slot: ks {2q, 2q+1}
    const int h = lane32 >> 4;         // field half

    float L0 = 0.f, L1 = 0.f, S0 = 0.f, S1 = 0.f, first = 0.f;
    const float* __restrict__ db = dense + b * ND;
    const int*   __restrict__ sb = sparse + b * NF;

    if (h == 0) {
#pragma unroll
        for (int d = 0; d < ND; ++d) {
            const float x = db[d];
            const unsigned r = Vt[(size_t)d * 16 + q];
            const float2 v = __half22float2(*(const __half2*)&r);
            first += x * w[d];
            const float a = x * v.x, c = x * v.y;
            L0 += a; S0 += a * a;
            L1 += c; S1 += c * c;
        }
    }

    const int f0 = h * 13;
#pragma unroll
    for (int ff = 0; ff < 13; ++ff) {
        const int f = f0 + ff;
        const int idx = ND + f * FS + sb[f];
        const unsigned r = Vt[(size_t)idx * 16 + q];
        const float2 v = __half22float2(*(const __half2*)&r);
        first += w[idx];               // same addr across the 16 q-lanes -> broadcast
        L0 += v.x; S0 += v.x * v.x;
        L1 += v.y; S1 += v.y * v.y;
    }

    // combine the two field-halves per k (xor 16 swaps halves)
    L0 += __shfl_xor(L0, 16);  S0 += __shfl_xor(S0, 16);
    L1 += __shfl_xor(L1, 16);  S1 += __shfl_xor(S1, 16);
    first += __shfl_xor(first, 16);

    float t = L0 * L0 - S0 + L1 * L1 - S1;
    t += __shfl_xor(t, 1);
    t += __shfl_xor(t, 2);
    t += __shfl_xor(t, 4);
    t += __shfl_xor(t, 8);             // sum over the 16 q-lanes

    if (lane32 == 0) {
        const float z = first + w0[0] + 0.5f * t;
        out[b] = 1.f / (1.f + __expf(-z));
    }
}

extern "C" void kernel_launch(void* const* d_in, const int* in_sizes, int n_in,
                              void* d_out, int out_size, void* d_ws, size_t ws_size,
                              hipStream_t stream) {
    const float* dense  = (const float*)d_in[0];
    const int*   sparse = (const int*)d_in[1];
    const float* w0     = (const float*)d_in[2];
    const float* w      = (const float*)d_in[3];
    const float* V      = (const float*)d_in[4];
    float* out = (float*)d_out;

    unsigned char* flags = (unsigned char*)d_ws;              // 2.6 MB
    unsigned*      Vt    = (unsigned*)((char*)d_ws + FL_PAD); // 166 MB, 256B-aligned

    hipMemsetAsync(flags, 0, FL_PAD, stream);                 // graph-capturable
    fm_mark<<<N_MARK / 256, 256, 0, stream>>>(sparse, flags);
    const int prep_threads = (FL + 3) / 4;
    fm_prep<<<(prep_threads + 255) / 256, 256, 0, stream>>>(V, flags, Vt);
    fm_gather<<<(FM_BATCH * 32) / 256, 256, 0, stream>>>(
        dense, sparse, w0, w, Vt, out);
}